// Round 15
// baseline (83.674 us; speedup 1.0000x reference)
//
#include <hip/hip_runtime.h>
#include <stdint.h>
#include <math.h>

typedef short bf16x8 __attribute__((ext_vector_type(8)));
typedef float f32x16 __attribute__((ext_vector_type(16)));
typedef unsigned int uint4v __attribute__((ext_vector_type(4)));

#define GAS __attribute__((address_space(1)))
#define LAS __attribute__((address_space(3)))

#define CDIM 128
#define NQ   4096
#define NK   16384
#define QT   64          // queries per block (2 waves x 32)
#define KTILE 32

__device__ __forceinline__ unsigned short f2bf(float f) {
    unsigned int u = __builtin_bit_cast(unsigned int, f);
    u = (u + 0x7fffu + ((u >> 16) & 1u)) >> 16;
    return (unsigned short)u;
}

__device__ __forceinline__ void gload_lds16(const void* g, void* l) {
    __builtin_amdgcn_global_load_lds((const GAS unsigned int*)g, (LAS unsigned int*)l, 16, 0, 0);
}

__device__ __forceinline__ unsigned cvtpk(float a, float b) {
    unsigned r;
    asm("v_cvt_pk_bf16_f32 %0, %1, %2" : "=v"(r) : "v"(a), "v"(b));
    return r;
}

// a' = lane<32 ? a : b[lane-32] ; b' = lane<32 ? a[lane+32] : b
__device__ __forceinline__ void swap32(unsigned& a, unsigned& b) {
    asm("v_permlane32_swap_b32 %0, %1" : "+v"(a), "+v"(b));
}

// ---------------- prep_q: Q[q][c] = bf16(conv2 (x) (feats_t * vt)) ----------------
__global__ void prep_q_kernel(const float* __restrict__ feats_t,
                              const float* __restrict__ v_t,
                              const float* __restrict__ w2,
                              unsigned int* __restrict__ Q32) {
    int idx = blockIdx.x * 256 + threadIdx.x;   // 262144 threads
    int q = idx & 4095, cp = idx >> 12;         // cp = c-pair 0..63
    int y = q >> 6, x = q & 63;
    const float* fb0 = feats_t + (size_t)(cp * 2) * 4096;
    const float* fb1 = fb0 + 4096;
    float wv[9];
#pragma unroll
    for (int i = 0; i < 9; ++i) wv[i] = w2[i];
    float acc0 = 0.f, acc1 = 0.f;
#pragma unroll
    for (int u = 0; u < 3; ++u) {
        int yy = y + u - 1;
        if ((unsigned)yy >= 64u) continue;
#pragma unroll
        for (int v = 0; v < 3; ++v) {
            int xx = x + v - 1;
            if ((unsigned)xx >= 64u) continue;
            float m = wv[u * 3 + v] * v_t[yy * 1024 + xx * 4];
            acc0 += m * fb0[yy * 64 + xx];
            acc1 += m * fb1[yy * 64 + xx];
        }
    }
    Q32[(size_t)q * 64 + cp] = (unsigned)f2bf(acc0) | ((unsigned)f2bf(acc1) << 16);
}

// ---------------- prep_p: P[c][rk] = fr*vr (f32) ; Vt2 = 32k-tiled bf16 ----------------
// Vt2 tile (32 keys, 16B chunks): chunk = jh*128 + c holds V[c][k = tile*32 + jh*8 .. +8)
__global__ void prep_p_kernel(const float* __restrict__ feats_ref,
                              const float* __restrict__ v_ref,
                              float* __restrict__ P,
                              unsigned short* __restrict__ Vt2) {
    int idx = blockIdx.x * 256 + threadIdx.x;   // 2M threads
    int c = idx >> 14, rk = idx & 16383;
    int r = rk >> 12, k4 = rk & 4095, ky = k4 >> 6, kx = k4 & 63;
    float v = feats_ref[idx] * v_ref[r * 65536 + ky * 1024 + kx * 4];
    P[idx] = v;
    Vt2[(size_t)(rk >> 5) * 4096 + (((rk >> 3) & 3) * 128 + c) * 8 + (rk & 7)] = f2bf(v);
}

// ---------------- prep_k2: Kt = 32k-tiled bf16 of conv1 (x) P ----------------
// Kt tile: chunk = cp*32 + rw holds K[rk = tile*32 + rw][c = cp*8 .. +8)
__global__ void prep_k2_kernel(const float* __restrict__ P,
                               const float* __restrict__ w1,
                               unsigned int* __restrict__ K32) {
    int idx = blockIdx.x * 256 + threadIdx.x;   // 1048576 threads
    int rk = idx & 16383, cp2 = idx >> 14;      // cp2 = c-pair 0..63
    int r = rk >> 12, k4 = rk & 4095, ky = k4 >> 6, kx = k4 & 63;
    const float* pb0 = P + (size_t)(cp2 * 2) * NK + r * 4096;
    const float* pb1 = pb0 + NK;
    float wv[9];
#pragma unroll
    for (int i = 0; i < 9; ++i) wv[i] = w1[i];
    float acc0 = 0.f, acc1 = 0.f;
#pragma unroll
    for (int u = 0; u < 3; ++u) {
        int yy = ky + u - 1;
        if ((unsigned)yy >= 64u) continue;
#pragma unroll
        for (int v = 0; v < 3; ++v) {
            int xx = kx + v - 1;
            if ((unsigned)xx >= 64u) continue;
            float w = wv[u * 3 + v];
            acc0 += w * pb0[yy * 64 + xx];
            acc1 += w * pb1[yy * 64 + xx];
        }
    }
    int tile = rk >> 5, rw = rk & 31;
    K32[(size_t)tile * 2048 + ((cp2 >> 2) * 32 + rw) * 4 + (cp2 & 3)] =
        (unsigned)f2bf(acc0) | ((unsigned)f2bf(acc1) << 16);
}

// ---- attn: 2 waves x 32q, KTILE=32, 32KB LDS dbuf, 4 blocks/CU phase-decorrelated ----
template<int KS>
__launch_bounds__(128, 2)
__global__ void attn_kernel(const unsigned short* __restrict__ Qg,
                            const unsigned short* __restrict__ Kt,
                            const unsigned short* __restrict__ Vt2,
                            float* __restrict__ Opart,
                            float* __restrict__ lpart) {
    constexpr int NITER = (NK / KS) / KTILE;                  // KS=16 -> 32
    __shared__ __align__(16) unsigned short KV[2][2][4096];   // [buf][K/V][8KB] = 32KB

    const int tid = threadIdx.x;
    const int wid = tid >> 6;
    const int lane = tid & 63;
    const int l31 = lane & 31;
    const int lh = lane >> 5;
    const int ks = blockIdx.x & (KS - 1);
    const int qt = blockIdx.x / KS;
    const int q0 = qt * QT + wid * 32;
    const int tile0 = ks * NITER;

    // Q fragments: lane holds Q[q0+l31][s*16 + lh*8 + j]
    bf16x8 qf[8];
#pragma unroll
    for (int s = 0; s < 8; ++s)
        qf[s] = *(const bf16x8*)(Qg + (size_t)(q0 + l31) * CDIM + s * 16 + lh * 8);

    f32x16 accO[4];
#pragma unroll
    for (int u = 0; u < 4; ++u)
#pragma unroll
        for (int r = 0; r < 16; ++r) accO[u][r] = 0.f;
    float l_acc = 0.f;

    // staging: per tile 512 chunks K + 512 chunks V; 128 threads -> 4+4 loads/thread
#define STAGE(nb, tg)                                                             \
    do {                                                                          \
        _Pragma("unroll") for (int j = 0; j < 4; ++j) {                           \
            int mb = (wid * 4 + j) * 64;                                          \
            gload_lds16(Kt + (size_t)(tg) * 4096 + (mb + lane) * 8,               \
                        &KV[(nb)][0][mb * 8]);                                    \
            gload_lds16(Vt2 + (size_t)(tg) * 4096 + (mb + lane) * 8,              \
                        &KV[(nb)][1][mb * 8]);                                    \
        }                                                                         \
    } while (0)

    STAGE(0, tile0);

#pragma unroll 1
    for (int it = 0; it < NITER; ++it) {
        const int bc = it & 1;
        __syncthreads();   // both waves done reading buf bc^1 -> safe to overwrite
        if (it + 1 < NITER) {
            STAGE(bc ^ 1, tile0 + it + 1);
            asm volatile("s_waitcnt vmcnt(8)" ::: "memory");   // tile-it loads drained
        } else {
            asm volatile("s_waitcnt vmcnt(0)" ::: "memory");
        }
        __syncthreads();   // both waves' tile-it chunks landed

        // S^T[k][q]: A = K (32k x 16c slice), B = Q (R10-validated offsets)
        f32x16 S;
#pragma unroll
        for (int r = 0; r < 16; ++r) S[r] = 0.f;
        __builtin_amdgcn_s_setprio(1);
#pragma unroll
        for (int s = 0; s < 8; ++s) {
            bf16x8 kf = *(const bf16x8*)(&KV[bc][0][((s * 2 + lh) * 32 + l31) * 8]);
            S = __builtin_amdgcn_mfma_f32_32x32x16_bf16(kf, qf[s], S, 0, 0, 0);
        }
        __builtin_amdgcn_s_setprio(0);

        // P = exp(S) (native); tree-structured row sum
        float e[16];
#pragma unroll
        for (int r = 0; r < 16; ++r) e[r] = __expf(S[r]);
        {
            float t0 = (e[0] + e[1]) + (e[2] + e[3]);
            float t1 = (e[4] + e[5]) + (e[6] + e[7]);
            float t2 = (e[8] + e[9]) + (e[10] + e[11]);
            float t3 = (e[12] + e[13]) + (e[14] + e[15]);
            l_acc += (t0 + t1) + (t2 + t3);
        }
        // pack + redistribute into PV B-frag order (verified R5-R14 mapping)
        unsigned a0 = cvtpk(e[0], e[1]),   a1 = cvtpk(e[2], e[3]);
        unsigned a2 = cvtpk(e[4], e[5]),   a3 = cvtpk(e[6], e[7]);
        unsigned a4 = cvtpk(e[8], e[9]),   a5 = cvtpk(e[10], e[11]);
        unsigned a6 = cvtpk(e[12], e[13]), a7 = cvtpk(e[14], e[15]);
        swap32(a0, a2); swap32(a1, a3); swap32(a4, a6); swap32(a5, a7);
        bf16x8 pA = __builtin_bit_cast(bf16x8, (uint4v){a0, a1, a2, a3});
        bf16x8 pB = __builtin_bit_cast(bf16x8, (uint4v){a4, a5, a6, a7});

        // O^T += V . P^T  (A = V 32c x 16k slices; 4 independent chains)
        __builtin_amdgcn_s_setprio(1);
#pragma unroll
        for (int u = 0; u < 4; ++u) {
            bf16x8 vfa = *(const bf16x8*)(&KV[bc][1][((lh) * 128 + u * 32 + l31) * 8]);
            accO[u] = __builtin_amdgcn_mfma_f32_32x32x16_bf16(vfa, pA, accO[u], 0, 0, 0);
            bf16x8 vfb = *(const bf16x8*)(&KV[bc][1][((2 + lh) * 128 + u * 32 + l31) * 8]);
            accO[u] = __builtin_amdgcn_mfma_f32_32x32x16_bf16(vfb, pB, accO[u], 0, 0, 0);
        }
        __builtin_amdgcn_s_setprio(0);
    }
#undef STAGE

    l_acc += __shfl_xor(l_acc, 32);
    if (lane < 32) lpart[ks * NQ + q0 + l31] = l_acc;
#pragma unroll
    for (int u = 0; u < 4; ++u)
#pragma unroll
        for (int r = 0; r < 16; ++r) {
            int c = u * 32 + (r & 3) + 8 * (r >> 2) + 4 * lh;
            Opart[((size_t)(ks * CDIM + c)) * NQ + q0 + l31] = accO[u][r];
        }
}

// ---------------- reduce: out[c][q] = sum_s Opart[s][c][q] / sum_s lpart[s][q] ----------------
template<int KS>
__global__ void reduce_kernel(const float* __restrict__ Opart,
                              const float* __restrict__ lpart,
                              float* __restrict__ out) {
    int i = blockIdx.x * 256 + threadIdx.x;
    int c = i >> 12, q = i & 4095;
    float den = 0.f, o = 0.f;
#pragma unroll
    for (int s = 0; s < KS; ++s) {
        den += lpart[s * NQ + q];
        o += Opart[((size_t)(s * CDIM + c)) * NQ + q];
    }
    out[(size_t)c * NQ + q] = o / den;
}

extern "C" void kernel_launch(void* const* d_in, const int* in_sizes, int n_in,
                              void* d_out, int out_size, void* d_ws, size_t ws_size,
                              hipStream_t stream) {
    (void)in_sizes; (void)n_in; (void)out_size;
    const float* feats_t   = (const float*)d_in[0];
    const float* feats_ref = (const float*)d_in[1];
    const float* v_t       = (const float*)d_in[2];
    const float* v_ref     = (const float*)d_in[3];
    const float* w1        = (const float*)d_in[4];  // conv1 -> K side
    const float* w2        = (const float*)d_in[6];  // conv2 -> Q side
    float* out = (float*)d_out;

    // ws: Q 1MB | Kt 4MB | Vt2 4MB | Opart (KS*2MB) | lpart ; P(f32, 8MB) aliases Opart
    const size_t opart_off = (size_t)(9u << 20);
    const size_t per_split = (size_t)NQ * CDIM * 4;            // 2MB
    const size_t need16 = opart_off + 16 * per_split + 16 * NQ * 4;
    const size_t need8  = opart_off + 8  * per_split + 8  * NQ * 4;
    if (ws_size < need8) return;

    char* ws = (char*)d_ws;
    unsigned int*   Q   = (unsigned int*)(ws);
    unsigned short* Kt  = (unsigned short*)(ws + (size_t)(1u << 20));
    unsigned short* Vt2 = (unsigned short*)(ws + (size_t)(5u << 20));
    float* Opart = (float*)(ws + opart_off);
    float* P     = Opart;   // consumed by prep_k2 before attn writes Opart

    hipLaunchKernelGGL(prep_q_kernel, dim3(1024), dim3(256), 0, stream, feats_t, v_t, w2, Q);
    hipLaunchKernelGGL(prep_p_kernel, dim3(8192), dim3(256), 0, stream, feats_ref, v_ref, P, Vt2);
    hipLaunchKernelGGL(prep_k2_kernel, dim3(4096), dim3(256), 0, stream, P, w1, (unsigned int*)Kt);

    if (ws_size >= need16) {
        float* lpart = (float*)(ws + opart_off + 16 * per_split);
        hipLaunchKernelGGL(HIP_KERNEL_NAME(attn_kernel<16>), dim3((NQ / QT) * 16), dim3(128), 0,
                           stream, (const unsigned short*)Q, Kt, Vt2, Opart, lpart);
        hipLaunchKernelGGL(HIP_KERNEL_NAME(reduce_kernel<16>), dim3(2048), dim3(256), 0,
                           stream, Opart, lpart, out);
    } else {
        float* lpart = (float*)(ws + opart_off + 8 * per_split);
        hipLaunchKernelGGL(HIP_KERNEL_NAME(attn_kernel<8>), dim3((NQ / QT) * 8), dim3(128), 0,
                           stream, (const unsigned short*)Q, Kt, Vt2, Opart, lpart);
        hipLaunchKernelGGL(HIP_KERNEL_NAME(reduce_kernel<8>), dim3(2048), dim3(256), 0,
                           stream, Opart, lpart, out);
    }
}